// Round 2
// baseline (591.590 us; speedup 1.0000x reference)
//
#include <hip/hip_runtime.h>

#define NCOL 110592          // 48*48*48
#define NCH  64              // channels C
#define CN   (NCOL * NCH)    // 7077888 elements per batch
#define NB   8

typedef __attribute__((ext_vector_type(8))) __bf16 bf16x8;
typedef __attribute__((ext_vector_type(4))) float  f32x4;

// ---------------------------------------------------------------------------
// K1: partial Gram G_partial = K_chunk * K_chunk^T via bf16 MFMA.
// A-frag and B-frag of a Gram share the same per-lane layout
// (row = lane&15, k = quad*8+j), so fragments load DIRECTLY from global.
// Block = 256 threads = 4 waves; wave w owns output row-tile w (16 rows),
// computes 4 column-tiles -> full 64x64 partial per block, no LDS.
// chunks=128 -> 1024 blocks -> 4 blocks/CU for latency hiding.
// ---------------------------------------------------------------------------
__global__ __launch_bounds__(256) void k_gram(const float* __restrict__ x,
                                              float* __restrict__ part,
                                              int steps) {
    const int b     = blockIdx.y;
    const int chunk = blockIdx.x;
    const int tid   = threadIdx.x;
    const int w     = tid >> 6;          // wave id 0..3 -> row-tile
    const int lane  = tid & 63;
    const int r     = lane & 15;
    const int q     = lane >> 4;

    const float* xb = x + (size_t)b * CN;

    f32x4 acc0 = {0.f, 0.f, 0.f, 0.f};
    f32x4 acc1 = {0.f, 0.f, 0.f, 0.f};
    f32x4 acc2 = {0.f, 0.f, 0.f, 0.f};
    f32x4 acc3 = {0.f, 0.f, 0.f, 0.f};

    const int kbase = chunk * steps * 32 + q * 8;

    for (int s = 0; s < steps; ++s) {
        const int k0 = kbase + s * 32;
        bf16x8 frag[4];
#pragma unroll
        for (int i = 0; i < 4; ++i) {
            const float* p = xb + (size_t)(i * 16 + r) * NCOL + k0;
            f32x4 lo = *(const f32x4*)p;
            f32x4 hi = *(const f32x4*)(p + 4);
            bf16x8 f;
            f[0] = (__bf16)lo[0]; f[1] = (__bf16)lo[1];
            f[2] = (__bf16)lo[2]; f[3] = (__bf16)lo[3];
            f[4] = (__bf16)hi[0]; f[5] = (__bf16)hi[1];
            f[6] = (__bf16)hi[2]; f[7] = (__bf16)hi[3];
            frag[i] = f;
        }
        // select this wave's A-fragment (avoid dynamic register indexing)
        bf16x8 af = (w == 0) ? frag[0] : (w == 1) ? frag[1]
                  : (w == 2) ? frag[2] : frag[3];
        acc0 = __builtin_amdgcn_mfma_f32_16x16x32_bf16(af, frag[0], acc0, 0, 0, 0);
        acc1 = __builtin_amdgcn_mfma_f32_16x16x32_bf16(af, frag[1], acc1, 0, 0, 0);
        acc2 = __builtin_amdgcn_mfma_f32_16x16x32_bf16(af, frag[2], acc2, 0, 0, 0);
        acc3 = __builtin_amdgcn_mfma_f32_16x16x32_bf16(af, frag[3], acc3, 0, 0, 0);
    }

    // C/D layout (16x16x32): col = lane&15, row = quad*4 + reg
    float* pp = part + (size_t)(b * gridDim.x + chunk) * 4096;
#pragma unroll
    for (int rr = 0; rr < 4; ++rr) {
        const int m = w * 16 + q * 4 + rr;
        pp[m * 64 + (0 * 16 + r)] = acc0[rr];
        pp[m * 64 + (1 * 16 + r)] = acc1[rr];
        pp[m * 64 + (2 * 16 + r)] = acc2[rr];
        pp[m * 64 + (3 * 16 + r)] = acc3[rr];
    }
}

// ---------------------------------------------------------------------------
// K2a: reduce partial Grams -> G[b][64*64].
// Grid (16,8): block owns 256 cells. tid&63 -> cell quad (f32x4), tid>>6 ->
// chunk phase (4-way split of the chunk loop kills the serial latency chain),
// LDS combine. Vectorized 16B loads.
// ---------------------------------------------------------------------------
__global__ __launch_bounds__(256) void k_reduce(const float* __restrict__ part,
                                                float* __restrict__ G,
                                                int chunks) {
    const int b    = blockIdx.y;
    const int cq   = threadIdx.x & 63;
    const int ph   = threadIdx.x >> 6;
    const int cell = blockIdx.x * 256 + cq * 4;

    f32x4 s = {0.f, 0.f, 0.f, 0.f};
    for (int p = ph; p < chunks; p += 4) {
        const f32x4 v = *(const f32x4*)(part + (size_t)(b * chunks + p) * 4096 + cell);
        s[0] += v[0]; s[1] += v[1]; s[2] += v[2]; s[3] += v[3];
    }

    __shared__ f32x4 red[4][64];
    red[ph][cq] = s;
    __syncthreads();
    if (ph == 0) {
        const f32x4 a = red[0][cq], b1 = red[1][cq];
        const f32x4 c = red[2][cq], d = red[3][cq];
        f32x4 o;
        o[0] = a[0] + b1[0] + c[0] + d[0];
        o[1] = a[1] + b1[1] + c[1] + d[1];
        o[2] = a[2] + b1[2] + c[2] + d[2];
        o[3] = a[3] + b1[3] + c[3] + d[3];
        *(f32x4*)(G + b * 4096 + cell) = o;
    }
}

// ---------------------------------------------------------------------------
// K2b: A' = gamma * sigmoid(G@G) + I   (G symmetric -> row-row dots).
// Identity folded in -> K3 is a single pass over x (no residual re-read).
// ---------------------------------------------------------------------------
__global__ __launch_bounds__(256) void k_affinity(const float* __restrict__ G,
                                                  const float* __restrict__ gptr,
                                                  float* __restrict__ A) {
    const int b = blockIdx.x;
    __shared__ float Gs[64 * 65];                 // +1 pad: break 64-stride conflicts
    const float* Gb = G + b * 4096;
    for (int i = threadIdx.x; i < 1024; i += 256) {
        const f32x4 v = *(const f32x4*)(Gb + i * 4);
        const int row = i >> 4;
        const int col = (i & 15) * 4;
        Gs[row * 65 + col + 0] = v[0];
        Gs[row * 65 + col + 1] = v[1];
        Gs[row * 65 + col + 2] = v[2];
        Gs[row * 65 + col + 3] = v[3];
    }
    __syncthreads();
    const float gamma = gptr[0];
    for (int id = threadIdx.x; id < 4096; id += 256) {
        const int c = id >> 6, e = id & 63;
        float dot = 0.f;
#pragma unroll
        for (int d = 0; d < 64; ++d)
            dot += Gs[c * 65 + d] * Gs[e * 65 + d];
        const float aff = 1.0f / (1.0f + __expf(-dot));
        A[b * 4096 + id] = gamma * aff + ((c == e) ? 1.0f : 0.0f);
    }
}

// ---------------------------------------------------------------------------
// K3: out = A' @ K, fp32 VALU, fully coalesced (memory-floor-bound).
// Thread owns 2 ADJACENT columns via float2 loads/stores: 512 B per
// wave-instruction, x read exactly once (identity inside A' gives "+x").
// VALU cost = 7.25 GFLOP / 157 TF = 46 us < 72 us HBM floor -> memory-bound.
// A' read with wave-uniform indices -> scalar (SGPR) loads, broadcast FMA.
// ---------------------------------------------------------------------------
__global__ __launch_bounds__(256) void k_apply(const float* __restrict__ x,
                                               const float* __restrict__ A,
                                               float* __restrict__ out) {
    const int b  = blockIdx.y;
    const int n0 = (blockIdx.x * 256 + threadIdx.x) * 2;
    const float* xb = x + (size_t)b * CN;
    float*       ob = out + (size_t)b * CN;
    const float* Ab = A + b * 4096;

    float2 acc[64];
#pragma unroll
    for (int c = 0; c < 64; ++c) { acc[c].x = 0.f; acc[c].y = 0.f; }

#pragma unroll 4
    for (int d = 0; d < 64; ++d) {
        const float2 k = *(const float2*)(xb + (size_t)d * NCOL + n0);
#pragma unroll
        for (int c = 0; c < 64; ++c) {
            const float a = Ab[d * 64 + c];   // A' symmetric: [d][c] == [c][d]
            acc[c].x += a * k.x;
            acc[c].y += a * k.y;
        }
    }

#pragma unroll
    for (int c = 0; c < 64; ++c)
        *(float2*)(ob + (size_t)c * NCOL + n0) = acc[c];
}

// ---------------------------------------------------------------------------
extern "C" void kernel_launch(void* const* d_in, const int* in_sizes, int n_in,
                              void* d_out, int out_size, void* d_ws, size_t ws_size,
                              hipStream_t stream) {
    const float* x    = (const float*)d_in[0];
    const float* gptr = (const float*)d_in[1];
    float*       out  = (float*)d_out;
    float*       ws   = (float*)d_ws;

    // 3456 k32-steps per batch must split evenly across chunks.
    int chunks = 128;
    auto need = [](int ch) { return (size_t)(8 * ch + 16) * 4096 * 4; };
    if (ws_size < need(128)) chunks = 64;
    if (ws_size < need(64))  chunks = 32;
    if (ws_size < need(32))  chunks = 8;
    if (ws_size < need(8))   chunks = 2;
    const int steps = 3456 / chunks;

    float* part = ws;
    float* G    = ws + (size_t)8 * chunks * 4096;
    float* Aff  = G + 8 * 4096;

    k_gram    <<<dim3(chunks, 8), 256, 0, stream>>>(x, part, steps);
    k_reduce  <<<dim3(16, 8),     256, 0, stream>>>(part, G, chunks);
    k_affinity<<<8,               256, 0, stream>>>(G, gptr, Aff);
    k_apply   <<<dim3(216, 8),    256, 0, stream>>>(x, Aff, out);
}

// Round 3
// 510.703 us; speedup vs baseline: 1.1584x; 1.1584x over previous
//
#include <hip/hip_runtime.h>

#define NCOL 110592          // 48*48*48
#define NCH  64              // channels C
#define CN   (NCOL * NCH)    // 7077888 elements per batch
#define NB   8

typedef __attribute__((ext_vector_type(8))) __bf16 bf16x8;
typedef __attribute__((ext_vector_type(4))) float  f32x4;

// ---------------------------------------------------------------------------
// K1: partial Gram G_partial = K_chunk * K_chunk^T via bf16 MFMA.
// A-frag and B-frag of a Gram share the same per-lane layout
// (row = lane&15, k = quad*8+j), so fragments load DIRECTLY from global.
// Block = 256 threads = 4 waves; wave w owns output row-tile w (16 rows),
// computes 4 column-tiles -> full 64x64 partial per block, no LDS.
// chunks=128 -> 1024 blocks -> 4 blocks/CU for latency hiding.
// ---------------------------------------------------------------------------
__global__ __launch_bounds__(256) void k_gram(const float* __restrict__ x,
                                              float* __restrict__ part,
                                              int steps) {
    const int b     = blockIdx.y;
    const int chunk = blockIdx.x;
    const int tid   = threadIdx.x;
    const int w     = tid >> 6;          // wave id 0..3 -> row-tile
    const int lane  = tid & 63;
    const int r     = lane & 15;
    const int q     = lane >> 4;

    const float* xb = x + (size_t)b * CN;

    f32x4 acc0 = {0.f, 0.f, 0.f, 0.f};
    f32x4 acc1 = {0.f, 0.f, 0.f, 0.f};
    f32x4 acc2 = {0.f, 0.f, 0.f, 0.f};
    f32x4 acc3 = {0.f, 0.f, 0.f, 0.f};

    const int kbase = chunk * steps * 32 + q * 8;

    for (int s = 0; s < steps; ++s) {
        const int k0 = kbase + s * 32;
        bf16x8 frag[4];
#pragma unroll
        for (int i = 0; i < 4; ++i) {
            const float* p = xb + (size_t)(i * 16 + r) * NCOL + k0;
            f32x4 lo = *(const f32x4*)p;
            f32x4 hi = *(const f32x4*)(p + 4);
            bf16x8 f;
            f[0] = (__bf16)lo[0]; f[1] = (__bf16)lo[1];
            f[2] = (__bf16)lo[2]; f[3] = (__bf16)lo[3];
            f[4] = (__bf16)hi[0]; f[5] = (__bf16)hi[1];
            f[6] = (__bf16)hi[2]; f[7] = (__bf16)hi[3];
            frag[i] = f;
        }
        // select this wave's A-fragment (avoid dynamic register indexing)
        bf16x8 af = (w == 0) ? frag[0] : (w == 1) ? frag[1]
                  : (w == 2) ? frag[2] : frag[3];
        acc0 = __builtin_amdgcn_mfma_f32_16x16x32_bf16(af, frag[0], acc0, 0, 0, 0);
        acc1 = __builtin_amdgcn_mfma_f32_16x16x32_bf16(af, frag[1], acc1, 0, 0, 0);
        acc2 = __builtin_amdgcn_mfma_f32_16x16x32_bf16(af, frag[2], acc2, 0, 0, 0);
        acc3 = __builtin_amdgcn_mfma_f32_16x16x32_bf16(af, frag[3], acc3, 0, 0, 0);
    }

    // C/D layout (16x16x32): col = lane&15, row = quad*4 + reg
    float* pp = part + (size_t)(b * gridDim.x + chunk) * 4096;
#pragma unroll
    for (int rr = 0; rr < 4; ++rr) {
        const int m = w * 16 + q * 4 + rr;
        pp[m * 64 + (0 * 16 + r)] = acc0[rr];
        pp[m * 64 + (1 * 16 + r)] = acc1[rr];
        pp[m * 64 + (2 * 16 + r)] = acc2[rr];
        pp[m * 64 + (3 * 16 + r)] = acc3[rr];
    }
}

// ---------------------------------------------------------------------------
// K2a: reduce partial Grams -> G[b][64*64].
// Grid (16,8): block owns 256 cells. tid&63 -> cell quad (f32x4), tid>>6 ->
// chunk phase (4-way split of the chunk loop kills the serial latency chain),
// LDS combine. Vectorized 16B loads.
// ---------------------------------------------------------------------------
__global__ __launch_bounds__(256) void k_reduce(const float* __restrict__ part,
                                                float* __restrict__ G,
                                                int chunks) {
    const int b    = blockIdx.y;
    const int cq   = threadIdx.x & 63;
    const int ph   = threadIdx.x >> 6;
    const int cell = blockIdx.x * 256 + cq * 4;

    f32x4 s = {0.f, 0.f, 0.f, 0.f};
    for (int p = ph; p < chunks; p += 4) {
        const f32x4 v = *(const f32x4*)(part + (size_t)(b * chunks + p) * 4096 + cell);
        s[0] += v[0]; s[1] += v[1]; s[2] += v[2]; s[3] += v[3];
    }

    __shared__ f32x4 red[4][64];
    red[ph][cq] = s;
    __syncthreads();
    if (ph == 0) {
        const f32x4 a = red[0][cq], b1 = red[1][cq];
        const f32x4 c = red[2][cq], d = red[3][cq];
        f32x4 o;
        o[0] = a[0] + b1[0] + c[0] + d[0];
        o[1] = a[1] + b1[1] + c[1] + d[1];
        o[2] = a[2] + b1[2] + c[2] + d[2];
        o[3] = a[3] + b1[3] + c[3] + d[3];
        *(f32x4*)(G + b * 4096 + cell) = o;
    }
}

// ---------------------------------------------------------------------------
// K2b: A' = gamma * sigmoid(G@G) + I   (G symmetric -> row-row dots).
// Identity folded in -> K3 is a single pass over x (no residual re-read).
// ---------------------------------------------------------------------------
__global__ __launch_bounds__(256) void k_affinity(const float* __restrict__ G,
                                                  const float* __restrict__ gptr,
                                                  float* __restrict__ A) {
    const int b = blockIdx.x;
    __shared__ float Gs[64 * 65];                 // +1 pad: break 64-stride conflicts
    const float* Gb = G + b * 4096;
    for (int i = threadIdx.x; i < 1024; i += 256) {
        const f32x4 v = *(const f32x4*)(Gb + i * 4);
        const int row = i >> 4;
        const int col = (i & 15) * 4;
        Gs[row * 65 + col + 0] = v[0];
        Gs[row * 65 + col + 1] = v[1];
        Gs[row * 65 + col + 2] = v[2];
        Gs[row * 65 + col + 3] = v[3];
    }
    __syncthreads();
    const float gamma = gptr[0];
    for (int id = threadIdx.x; id < 4096; id += 256) {
        const int c = id >> 6, e = id & 63;
        float dot = 0.f;
#pragma unroll
        for (int d = 0; d < 64; ++d)
            dot += Gs[c * 65 + d] * Gs[e * 65 + d];
        const float aff = 1.0f / (1.0f + __expf(-dot));
        A[b * 4096 + id] = gamma * aff + ((c == e) ? 1.0f : 0.0f);
    }
}

// ---------------------------------------------------------------------------
// K3: out = A' @ K, fp32 VALU, fully coalesced, ONE column per thread.
// Accumulator = 64 fp32 (not 128): fits the VGPR budget with room to spare.
// __launch_bounds__(256, 4) pins the cap at 128 VGPRs -> provably no spill
// (round-2 post-mortem: 2-col version needed ~140, allocator capped at 96,
// spilled accumulators to scratch -> 213 us. This was the real round-0/2 cost.)
// Wave load/store = 64 consecutive floats = 256 B, fully coalesced.
// VALU floor 46 us < HBM floor 72 us (453 MB @ 6.3 TB/s) -> memory-bound.
// A' rows are wave-uniform -> SGPR broadcast operands in the FMAs.
// ---------------------------------------------------------------------------
__global__ __launch_bounds__(256, 4) void k_apply(const float* __restrict__ x,
                                                  const float* __restrict__ A,
                                                  float* __restrict__ out) {
    const int b = blockIdx.y;
    const int n = blockIdx.x * 256 + threadIdx.x;   // one column per thread
    const float* xb = x + (size_t)b * CN + n;
    float*       ob = out + (size_t)b * CN + n;
    const float* Ab = A + b * 4096;

    float acc[64];
#pragma unroll
    for (int c = 0; c < 64; ++c) acc[c] = 0.f;

#pragma unroll 8
    for (int d = 0; d < 64; ++d) {
        const float k = xb[(size_t)d * NCOL];       // 8 loads in flight (unroll)
#pragma unroll
        for (int c = 0; c < 64; ++c)
            acc[c] += Ab[d * 64 + c] * k;           // SGPR-broadcast FMA
    }

#pragma unroll
    for (int c = 0; c < 64; ++c)
        ob[(size_t)c * NCOL] = acc[c];
}

// ---------------------------------------------------------------------------
extern "C" void kernel_launch(void* const* d_in, const int* in_sizes, int n_in,
                              void* d_out, int out_size, void* d_ws, size_t ws_size,
                              hipStream_t stream) {
    const float* x    = (const float*)d_in[0];
    const float* gptr = (const float*)d_in[1];
    float*       out  = (float*)d_out;
    float*       ws   = (float*)d_ws;

    // 3456 k32-steps per batch must split evenly across chunks.
    int chunks = 128;
    auto need = [](int ch) { return (size_t)(8 * ch + 16) * 4096 * 4; };
    if (ws_size < need(128)) chunks = 64;
    if (ws_size < need(64))  chunks = 32;
    if (ws_size < need(32))  chunks = 8;
    if (ws_size < need(8))   chunks = 2;
    const int steps = 3456 / chunks;

    float* part = ws;
    float* G    = ws + (size_t)8 * chunks * 4096;
    float* Aff  = G + 8 * 4096;

    k_gram    <<<dim3(chunks, 8), 256, 0, stream>>>(x, part, steps);
    k_reduce  <<<dim3(16, 8),     256, 0, stream>>>(part, G, chunks);
    k_affinity<<<8,               256, 0, stream>>>(G, gptr, Aff);
    k_apply   <<<dim3(432, 8),    256, 0, stream>>>(x, Aff, out);
}